// Round 11
// baseline (282.665 us; speedup 1.0000x reference)
//
#include <hip/hip_runtime.h>
#include <hip/hip_bf16.h>

#define N_NODES 100000
#define N_EDGES 3200000
#define N_GRAPHS 512
#define NBUK 782               // dst buckets of 128 nodes
#define CAP 4608               // packed slots per bucket (mean 4096, sigma~64)
#define CCAP 5632              // csr slots per bucket (ceil16-padded degs, mean ~5120)
#define FILL_CHUNK 8192
#define FILL_BLOCKS ((N_EDGES + FILL_CHUNK - 1) / FILL_CHUNK)   // 391
#define GEMM1_BLOCKS ((N_NODES + 63) / 64)                      // 1563

__device__ __forceinline__ float blo(unsigned v) { return __uint_as_float(v << 16); }
__device__ __forceinline__ float bhi(unsigned v) { return __uint_as_float(v & 0xffff0000u); }

// ---------- fat pass 1: binfill (blocks 0..390)  ||  gemm1 unscaled (rest) ----------
// binfill scan rewritten as wave-level shfl_up scan: 2 barriers instead of 20.
__global__ __launch_bounds__(1024) void k_fatA(const int* __restrict__ ei,
                                               int* __restrict__ gcnt,
                                               unsigned* __restrict__ packed,
                                               const float* __restrict__ x,
                                               const float* __restrict__ W1,
                                               float* __restrict__ H1u) {
    __shared__ __align__(16) char smem[49152];
    int t = threadIdx.x;
    if (blockIdx.x < FILL_BLOCKS) {
        unsigned* buf = (unsigned*)smem;                       // 32768 B
        int* h    = (int*)(smem + 32768);
        int* base = (int*)(smem + 35896);
        int* sb   = (int*)(smem + 39024);
        int* ws   = (int*)(smem + 42152);                      // 16 wave sums
        for (int i = t; i < NBUK; i += 1024) h[i] = 0;
        __syncthreads();
        int s0 = blockIdx.x * FILL_CHUNK;
        int ng = min(FILL_CHUNK, N_EDGES - s0) >> 2;
        const int4* src4 = (const int4*)(ei + s0);
        const int4* dst4 = (const int4*)(ei + N_EDGES + s0);
        int4 sv[2], dv[2];
        int  rk[2][4];
#pragma unroll
        for (int g = 0; g < 2; g++) {
            int gi = t + g * 1024;
            if (gi < ng) {
                sv[g] = src4[gi];
                dv[g] = dst4[gi];
                rk[g][0] = atomicAdd(&h[dv[g].x >> 7], 1);
                rk[g][1] = atomicAdd(&h[dv[g].y >> 7], 1);
                rk[g][2] = atomicAdd(&h[dv[g].z >> 7], 1);
                rk[g][3] = atomicAdd(&h[dv[g].w >> 7], 1);
            }
        }
        __syncthreads();
        for (int i = t; i < NBUK; i += 1024) {
            int c = h[i];
            base[i] = c ? atomicAdd(&gcnt[i], c) : 0;
        }
        // wave-level exclusive scan of h[0..NBUK)
        int lane = t & 63, wv = t >> 6;
        int hval = (t < NBUK) ? h[t] : 0;
        int v = hval;
#pragma unroll
        for (int d2 = 1; d2 < 64; d2 <<= 1) {
            int o = __shfl_up(v, d2);
            if (lane >= d2) v += o;
        }
        if (lane == 63) ws[wv] = v;
        __syncthreads();
        if (wv == 0) {
            int s = (lane < 16) ? ws[lane] : 0;
            int sv2 = s;
#pragma unroll
            for (int d2 = 1; d2 < 16; d2 <<= 1) {
                int o = __shfl_up(sv2, d2);
                if (lane >= d2) sv2 += o;
            }
            if (lane < 16) ws[lane] = sv2 - s;   // exclusive wave offsets
        }
        __syncthreads();
        if (t < NBUK) sb[t] = v + ws[wv] - hval;
        __syncthreads();
#pragma unroll
        for (int g = 0; g < 2; g++) {
            int gi = t + g * 1024;
            if (gi < ng) {
                int s[4] = {sv[g].x, sv[g].y, sv[g].z, sv[g].w};
                int d[4] = {dv[g].x, dv[g].y, dv[g].z, dv[g].w};
#pragma unroll
                for (int k = 0; k < 4; k++) {
                    int bk = d[k] >> 7;
                    buf[sb[bk] + rk[g][k]] = (unsigned)s[k] | (((unsigned)d[k] & 127u) << 17);
                }
            }
        }
        __syncthreads();
        int w = t >> 6;
        for (int bk = w; bk < NBUK; bk += 16) {
            int c = h[bk];
            if (!c) continue;
            unsigned* gp = packed + (size_t)bk * CAP + base[bk];
            int lb = sb[bk];
            for (int j = lane; j < c; j += 64) gp[j] = buf[lb + j];
        }
    } else {
        // ---- gemm1u branch: H1u = x @ W1 (f32, unscaled), 64 rows/block, 2 rows/thread ----
        float* Ws = (float*)smem;              // 16384 B
        float* xs = (float*)(smem + 16384);    // 32768 B
        int b = blockIdx.x - FILL_BLOCKS;
        ((float4*)Ws)[t] = ((const float4*)W1)[t];
        int row0 = b * 64;
        const float4* x4 = (const float4*)(x + (size_t)row0 * 128);
        float4* xs4 = (float4*)xs;
        int maxr = min(64, N_NODES - row0);
        int nf4 = maxr * 32;
#pragma unroll
        for (int i = 0; i < 8; i++) {
            int idx = t + i * 1024;
            if (idx < nf4) xs4[idx] = x4[idx];
        }
        __syncthreads();
        int col = t & 31;
        int g = t >> 5;
        int r0 = 2 * g, r1 = 2 * g + 1;
        const float4* xa4 = xs4 + r0 * 32;
        const float4* xb4 = xs4 + r1 * 32;
        float a0 = 0.f, a1 = 0.f;
#pragma unroll 8
        for (int k4 = 0; k4 < 32; k4++) {
            float4 xa = xa4[k4];
            float4 xb = xb4[k4];
            float w0 = Ws[(k4 * 4 + 0) * 32 + col];
            float w1 = Ws[(k4 * 4 + 1) * 32 + col];
            float w2 = Ws[(k4 * 4 + 2) * 32 + col];
            float w3 = Ws[(k4 * 4 + 3) * 32 + col];
            a0 += xa.x * w0 + xa.y * w1 + xa.z * w2 + xa.w * w3;
            a1 += xb.x * w0 + xb.y * w1 + xb.z * w2 + xb.w * w3;
        }
        if (row0 + r0 < N_NODES) H1u[(size_t)(row0 + r0) * 32 + col] = a0;
        if (row0 + r1 < N_NODES) H1u[(size_t)(row0 + r1) * 32 + col] = a1;
    }
}

// ---------- pass 2: deg/rp/rpe/dinv + ceil16-PADDED slotted CSR + H1 scale ----------
// Pad slots hold dummy node N_NODES (zero H row) -> gather needs no per-lane
// predication. Scan is wave-level (2 barriers).
__global__ __launch_bounds__(512) void k_csr(const unsigned* __restrict__ packed,
                                             const int* __restrict__ gcnt,
                                             int* __restrict__ rp, int* __restrict__ rpe,
                                             float* __restrict__ dinv,
                                             int* __restrict__ csr,
                                             const float* __restrict__ H1u,
                                             __hip_bfloat16* __restrict__ H1s) {
    __shared__ int deg[128];
    __shared__ int nb0[128];
    __shared__ float dsh[128];
    __shared__ int wsum0;
    __shared__ int ntot;
    __shared__ int lcsr[CCAP] __attribute__((aligned(16)));
    int t = threadIdx.x;
    int b = blockIdx.x;
    if (t < 128) deg[t] = 0;
    __syncthreads();
    int n = gcnt[b];
    const unsigned* pb = packed + (size_t)b * CAP;
    unsigned pv[3][4];
    int rk[3][4];
#pragma unroll
    for (int g = 0; g < 3; g++) {
        int i0 = 4 * (t + g * 512);
        if (i0 < n) {
            if (i0 + 3 < n) {
                uint4 p = *(const uint4*)(pb + i0);
                pv[g][0] = p.x; pv[g][1] = p.y; pv[g][2] = p.z; pv[g][3] = p.w;
            } else {
#pragma unroll
                for (int k = 0; k < 4; k++) pv[g][k] = (i0 + k < n) ? pb[i0 + k] : 0u;
            }
#pragma unroll
            for (int k = 0; k < 4; k++)
                if (i0 + k < n) rk[g][k] = atomicAdd(&deg[pv[g][k] >> 17], 1);
        }
    }
    __syncthreads();
    // wave-level scan over padded degrees (threads 0..127 = waves 0,1)
    int lane = t & 63;
    int d = (t < 128) ? deg[t] : 0;
    int p16 = (d + 15) & ~15;
    int v = (t < 128) ? p16 : 0;
#pragma unroll
    for (int d2 = 1; d2 < 64; d2 <<= 1) {
        int o = __shfl_up(v, d2);
        if (lane >= d2) v += o;
    }
    if (t == 63) wsum0 = v;
    __syncthreads();
    if (t < 128) {
        int inc = v + ((t >= 64) ? wsum0 : 0);
        int l0 = inc - p16;
        nb0[t] = l0;
        float di = rsqrtf((float)d + 1.0f);
        dsh[t] = di;
        int node = b * 128 + t;
        if (node < N_NODES) {
            rp[node] = b * CCAP + l0;
            rpe[node] = b * CCAP + l0 + p16;
            dinv[node] = di;
        }
        for (int j = d; j < p16; j++) lcsr[l0 + j] = N_NODES;   // dummy pads
        if (t == 127) ntot = l0 + p16;
    }
    __syncthreads();
#pragma unroll
    for (int g = 0; g < 3; g++) {
        int i0 = 4 * (t + g * 512);
        if (i0 < n) {
#pragma unroll
            for (int k = 0; k < 4; k++) {
                if (i0 + k < n) {
                    unsigned p = pv[g][k];
                    lcsr[nb0[p >> 17] + rk[g][k]] = (int)(p & 0x1FFFFu);
                }
            }
        }
    }
    __syncthreads();
    int nq = (ntot + 3) >> 2;
    int4* dst4 = (int4*)(csr + (size_t)b * CCAP);
    const int4* sl4 = (const int4*)lcsr;
    for (int i = t; i < nq; i += 512) dst4[i] = sl4[i];
    // ---- H1 scale epilogue: 128 rows x 32 f32 -> bf16, x dinv ----
    for (int i = t; i < 1024; i += 512) {
        int row = i >> 3, q = i & 7;
        int node = b * 128 + row;
        if (node < N_NODES) {
            float4 fv = ((const float4*)H1u)[(size_t)node * 8 + q];
            float di = dsh[row];
            __hip_bfloat16 tmp[4];
            tmp[0] = __float2bfloat16(fv.x * di);
            tmp[1] = __float2bfloat16(fv.y * di);
            tmp[2] = __float2bfloat16(fv.z * di);
            tmp[3] = __float2bfloat16(fv.w * di);
            *(uint2*)(H1s + (size_t)node * 32 + q * 4) = *(uint2*)tmp;
        }
    }
    // dummy H1s row (read by gather pads) = zeros
    if (b == 0 && t < 16) ((unsigned*)(H1s + (size_t)N_NODES * 32))[t] = 0u;
}

// ---------- aggregation: wave per node, 4 lanes x uint4 per row, padded CSR ----------
// No per-lane predication: pdeg is a multiple of 16, pads hit the zero dummy row
// (hot L1 line). The k-guard is wave-uniform.
__global__ void k_gather(const __hip_bfloat16* __restrict__ Hs, const float* __restrict__ dinv,
                         const int* __restrict__ rp, const int* __restrict__ rpe,
                         const int* __restrict__ csr,
                         const float* __restrict__ bias, float* __restrict__ hout) {
    int wid = (blockIdx.x * 256 + threadIdx.x) >> 6;
    if (wid >= N_NODES) return;
    const uint4* H4 = (const uint4*)Hs;          // row = 4 x uint4 (64B)
    int lane = threadIdx.x & 63;
    int fb = lane & 3;
    int es = lane >> 2;
    int beg = rp[wid];
    int pdeg = rpe[wid] - beg;                   // ceil16(deg)
    float a0=0.f,a1=0.f,a2=0.f,a3=0.f,a4=0.f,a5=0.f,a6=0.f,a7=0.f;
    for (int eb = 0; eb < pdeg; eb += 64) {
        int cv = csr[beg + eb + lane];
#pragma unroll
        for (int k = 0; k < 4; k++) {
            if (eb + 16 * k < pdeg) {            // wave-uniform
                int src = __shfl(cv, es + 16 * k);
                uint4 v = H4[(size_t)src * 4 + fb];
                a0 += blo(v.x); a1 += bhi(v.x);
                a2 += blo(v.y); a3 += bhi(v.y);
                a4 += blo(v.z); a5 += bhi(v.z);
                a6 += blo(v.w); a7 += bhi(v.w);
            }
        }
    }
#pragma unroll
    for (int m = 4; m <= 32; m <<= 1) {
        a0 += __shfl_xor(a0, m); a1 += __shfl_xor(a1, m);
        a2 += __shfl_xor(a2, m); a3 += __shfl_xor(a3, m);
        a4 += __shfl_xor(a4, m); a5 += __shfl_xor(a5, m);
        a6 += __shfl_xor(a6, m); a7 += __shfl_xor(a7, m);
    }
    if (es == 0) {
        float di = dinv[wid];
        uint4 vw = H4[(size_t)wid * 4 + fb];
        float4 bA = *(const float4*)(bias + fb * 8);
        float4 bB = *(const float4*)(bias + fb * 8 + 4);
        float4 oA, oB;
        oA.x = fmaxf((a0 + blo(vw.x)) * di + bA.x, 0.f);
        oA.y = fmaxf((a1 + bhi(vw.x)) * di + bA.y, 0.f);
        oA.z = fmaxf((a2 + blo(vw.y)) * di + bA.z, 0.f);
        oA.w = fmaxf((a3 + bhi(vw.y)) * di + bA.w, 0.f);
        oB.x = fmaxf((a4 + blo(vw.z)) * di + bB.x, 0.f);
        oB.y = fmaxf((a5 + bhi(vw.z)) * di + bB.y, 0.f);
        oB.z = fmaxf((a6 + blo(vw.w)) * di + bB.z, 0.f);
        oB.w = fmaxf((a7 + bhi(vw.w)) * di + bB.w, 0.f);
        float* o = hout + (size_t)wid * 32 + fb * 8;
        *(float4*)o = oA;
        *(float4*)(o + 4) = oB;
    }
}

// ---------- H2s = bf16( (h1 @ W2) * dinv[row] ) ----------
__global__ void k_gemm2(const float* __restrict__ h1, const float* __restrict__ W2,
                        const float* __restrict__ dinv, __hip_bfloat16* __restrict__ H2s) {
    __shared__ float Ws[32 * 32];
    __shared__ float xs[32 * 32];
    int t = threadIdx.x;
    ((float4*)Ws)[t] = ((const float4*)W2)[t];
    int row0 = blockIdx.x * 32;
    ((float4*)xs)[t] = ((const float4*)(h1 + (size_t)row0 * 32))[t];
    __syncthreads();
    int col = t & 31;
    int rb = (t >> 5) * 4;
    float a0 = 0.f, a1 = 0.f, a2 = 0.f, a3 = 0.f;
#pragma unroll
    for (int k = 0; k < 32; k++) {
        float w = Ws[k * 32 + col];
        a0 += xs[(rb + 0) * 32 + k] * w;
        a1 += xs[(rb + 1) * 32 + k] * w;
        a2 += xs[(rb + 2) * 32 + k] * w;
        a3 += xs[(rb + 3) * 32 + k] * w;
    }
    int r = row0 + rb;
    __hip_bfloat16* o = H2s + (size_t)r * 32 + col;
    o[0]  = __float2bfloat16(a0 * dinv[r + 0]);
    o[32] = __float2bfloat16(a1 * dinv[r + 1]);
    o[64] = __float2bfloat16(a2 * dinv[r + 2]);
    o[96] = __float2bfloat16(a3 * dinv[r + 3]);
    // dummy H2s row (read by gather2 pads) = zeros
    if (blockIdx.x == 0 && t < 16) ((unsigned*)(H2s + (size_t)N_NODES * 32))[t] = 0u;
}

// ---------- per-graph mean pool + head (no atomics; batch is sorted) ----------
__global__ __launch_bounds__(256) void k_pool(const float* __restrict__ h2,
                                              const int* __restrict__ batch,
                                              const float* __restrict__ Wl,
                                              const float* __restrict__ bl,
                                              float* __restrict__ out) {
    __shared__ float red[256];
    __shared__ float pooled[32];
    int g = blockIdx.x;
    int t = threadIdx.x;
    int lo = 0, hi = N_NODES;
    while (lo < hi) { int m = (lo + hi) >> 1; if (batch[m] < g) lo = m + 1; else hi = m; }
    int s = lo;
    hi = N_NODES;
    while (lo < hi) { int m = (lo + hi) >> 1; if (batch[m] < g + 1) lo = m + 1; else hi = m; }
    int e = lo;
    int f = t & 31, r0 = t >> 5;
    float acc = 0.f;
    for (int r = s + r0; r < e; r += 8) acc += h2[(size_t)r * 32 + f];
    red[t] = acc;
    __syncthreads();
    for (int off = 128; off >= 32; off >>= 1) {
        if (t < off) red[t] += red[t + off];
        __syncthreads();
    }
    if (t < 32) pooled[t] = red[t] / fmaxf((float)(e - s), 1.0f);
    __syncthreads();
    if (t < 2) {
        float a = bl[t];
#pragma unroll
        for (int k = 0; k < 32; k++) a += pooled[k] * Wl[k * 2 + t];
        out[g * 2 + t] = a;
    }
}

extern "C" void kernel_launch(void* const* d_in, const int* in_sizes, int n_in,
                              void* d_out, int out_size, void* d_ws, size_t ws_size,
                              hipStream_t stream) {
    const float* x    = (const float*)d_in[0];
    const int*   ei   = (const int*)d_in[1];
    const int*   batch= (const int*)d_in[2];
    const float* W1   = (const float*)d_in[3];
    const float* b1   = (const float*)d_in[4];
    const float* W2   = (const float*)d_in[5];
    const float* b2   = (const float*)d_in[6];
    const float* Wl   = (const float*)d_in[7];
    const float* bl   = (const float*)d_in[8];
    float* out = (float*)d_out;

    char* w = (char*)d_ws;
    size_t off = 0;
    auto take = [&](size_t bytes) -> char* {
        char* p = w + off;
        off = (off + bytes + 255) & ~(size_t)255;
        return p;
    };
    // +1 dummy row on H1s/H2s for gather pads
    __hip_bfloat16* H1s = (__hip_bfloat16*)take((size_t)(N_NODES + 1) * 32 * 2);
    // h1: H1u (f32, fatA->csr), then relu'd h1 (gather1->gemm2), then h2 (gather2->pool)
    float*          h1  = (float*)take((size_t)N_NODES * 32 * 4);
    // packed (14.4 MB) and H2s (6.4 MB) alias: packed dies at k_csr; H2s born at k_gemm2.
    char*           shared = take((size_t)NBUK * CAP * 4);
    unsigned*       packed = (unsigned*)shared;
    __hip_bfloat16* H2s    = (__hip_bfloat16*)shared;
    int*      csr    = (int*)  take((size_t)NBUK * CCAP * 4 + 1024);   // +pad for 63-slot overread
    float*    dinv   = (float*)take((size_t)N_NODES * 4);
    int*      rp     = (int*)  take((size_t)N_NODES * 4);
    int*      rpe    = (int*)  take((size_t)N_NODES * 4);
    int*      gcnt   = (int*)  take((size_t)NBUK * 4);

    hipMemsetAsync(gcnt, 0, (size_t)NBUK * 4, stream);

    k_fatA  <<<FILL_BLOCKS + GEMM1_BLOCKS, 1024, 0, stream>>>(ei, gcnt, packed, x, W1, h1);
    k_csr   <<<NBUK, 512, 0, stream>>>(packed, gcnt, rp, rpe, dinv, csr, h1, H1s);
    k_gather<<<N_NODES / 4, 256, 0, stream>>>(H1s, dinv, rp, rpe, csr, b1, h1);
    k_gemm2 <<<N_NODES / 32, 256, 0, stream>>>(h1, W2, dinv, H2s);
    k_gather<<<N_NODES / 4, 256, 0, stream>>>(H2s, dinv, rp, rpe, csr, b2, h1);
    k_pool  <<<N_GRAPHS, 256, 0, stream>>>(h1, batch, Wl, bl, out);
}

// Round 12
// 254.964 us; speedup vs baseline: 1.1086x; 1.1086x over previous
//
#include <hip/hip_runtime.h>
#include <hip/hip_bf16.h>

#define N_NODES 100000
#define N_EDGES 3200000
#define N_GRAPHS 512
#define NBUK 782               // dst buckets of 128 nodes
#define CAP 4608               // packed slots per bucket (mean 4096, sigma~64)
#define CCAP 5632              // csr slots per bucket (ceil16-padded degs, mean ~5120)
#define FILL_CHUNK 8192
#define FILL_BLOCKS ((N_EDGES + FILL_CHUNK - 1) / FILL_CHUNK)   // 391
#define GEMM1_BLOCKS ((N_NODES + 63) / 64)                      // 1563

__device__ __forceinline__ float blo(unsigned v) { return __uint_as_float(v << 16); }
__device__ __forceinline__ float bhi(unsigned v) { return __uint_as_float(v & 0xffff0000u); }

// ---------- fat pass 1: binfill (blocks 0..390)  ||  gemm1 unscaled (rest) ----------
__global__ __launch_bounds__(1024) void k_fatA(const int* __restrict__ ei,
                                               int* __restrict__ gcnt,
                                               unsigned* __restrict__ packed,
                                               const float* __restrict__ x,
                                               const float* __restrict__ W1,
                                               float* __restrict__ H1u) {
    __shared__ __align__(16) char smem[49152];
    int t = threadIdx.x;
    if (blockIdx.x < FILL_BLOCKS) {
        unsigned* buf = (unsigned*)smem;                       // 32768 B
        int* h    = (int*)(smem + 32768);
        int* base = (int*)(smem + 35896);
        int* sb   = (int*)(smem + 39024);
        int* ws   = (int*)(smem + 42152);                      // 16 wave sums
        for (int i = t; i < NBUK; i += 1024) h[i] = 0;
        __syncthreads();
        int s0 = blockIdx.x * FILL_CHUNK;
        int ng = min(FILL_CHUNK, N_EDGES - s0) >> 2;
        const int4* src4 = (const int4*)(ei + s0);
        const int4* dst4 = (const int4*)(ei + N_EDGES + s0);
        int4 sv[2], dv[2];
        int  rk[2][4];
#pragma unroll
        for (int g = 0; g < 2; g++) {
            int gi = t + g * 1024;
            if (gi < ng) {
                sv[g] = src4[gi];
                dv[g] = dst4[gi];
                rk[g][0] = atomicAdd(&h[dv[g].x >> 7], 1);
                rk[g][1] = atomicAdd(&h[dv[g].y >> 7], 1);
                rk[g][2] = atomicAdd(&h[dv[g].z >> 7], 1);
                rk[g][3] = atomicAdd(&h[dv[g].w >> 7], 1);
            }
        }
        __syncthreads();
        for (int i = t; i < NBUK; i += 1024) {
            int c = h[i];
            base[i] = c ? atomicAdd(&gcnt[i], c) : 0;
        }
        // wave-level exclusive scan of h[0..NBUK)
        int lane = t & 63, wv = t >> 6;
        int hval = (t < NBUK) ? h[t] : 0;
        int v = hval;
#pragma unroll
        for (int d2 = 1; d2 < 64; d2 <<= 1) {
            int o = __shfl_up(v, d2);
            if (lane >= d2) v += o;
        }
        if (lane == 63) ws[wv] = v;
        __syncthreads();
        if (wv == 0) {
            int s = (lane < 16) ? ws[lane] : 0;
            int sv2 = s;
#pragma unroll
            for (int d2 = 1; d2 < 16; d2 <<= 1) {
                int o = __shfl_up(sv2, d2);
                if (lane >= d2) sv2 += o;
            }
            if (lane < 16) ws[lane] = sv2 - s;   // exclusive wave offsets
        }
        __syncthreads();
        if (t < NBUK) sb[t] = v + ws[wv] - hval;
        __syncthreads();
#pragma unroll
        for (int g = 0; g < 2; g++) {
            int gi = t + g * 1024;
            if (gi < ng) {
                int s[4] = {sv[g].x, sv[g].y, sv[g].z, sv[g].w};
                int d[4] = {dv[g].x, dv[g].y, dv[g].z, dv[g].w};
#pragma unroll
                for (int k = 0; k < 4; k++) {
                    int bk = d[k] >> 7;
                    buf[sb[bk] + rk[g][k]] = (unsigned)s[k] | (((unsigned)d[k] & 127u) << 17);
                }
            }
        }
        __syncthreads();
        int w = t >> 6;
        for (int bk = w; bk < NBUK; bk += 16) {
            int c = h[bk];
            if (!c) continue;
            unsigned* gp = packed + (size_t)bk * CAP + base[bk];
            int lb = sb[bk];
            for (int j = lane; j < c; j += 64) gp[j] = buf[lb + j];
        }
    } else {
        // ---- gemm1u branch: H1u = x @ W1 (f32, unscaled), 64 rows/block, 2 rows/thread ----
        float* Ws = (float*)smem;              // 16384 B
        float* xs = (float*)(smem + 16384);    // 32768 B
        int b = blockIdx.x - FILL_BLOCKS;
        ((float4*)Ws)[t] = ((const float4*)W1)[t];
        int row0 = b * 64;
        const float4* x4 = (const float4*)(x + (size_t)row0 * 128);
        float4* xs4 = (float4*)xs;
        int maxr = min(64, N_NODES - row0);
        int nf4 = maxr * 32;
#pragma unroll
        for (int i = 0; i < 8; i++) {
            int idx = t + i * 1024;
            if (idx < nf4) xs4[idx] = x4[idx];
        }
        __syncthreads();
        int col = t & 31;
        int g = t >> 5;
        int r0 = 2 * g, r1 = 2 * g + 1;
        const float4* xa4 = xs4 + r0 * 32;
        const float4* xb4 = xs4 + r1 * 32;
        float a0 = 0.f, a1 = 0.f;
#pragma unroll 8
        for (int k4 = 0; k4 < 32; k4++) {
            float4 xa = xa4[k4];
            float4 xb = xb4[k4];
            float w0 = Ws[(k4 * 4 + 0) * 32 + col];
            float w1 = Ws[(k4 * 4 + 1) * 32 + col];
            float w2 = Ws[(k4 * 4 + 2) * 32 + col];
            float w3 = Ws[(k4 * 4 + 3) * 32 + col];
            a0 += xa.x * w0 + xa.y * w1 + xa.z * w2 + xa.w * w3;
            a1 += xb.x * w0 + xb.y * w1 + xb.z * w2 + xb.w * w3;
        }
        if (row0 + r0 < N_NODES) H1u[(size_t)(row0 + r0) * 32 + col] = a0;
        if (row0 + r1 < N_NODES) H1u[(size_t)(row0 + r1) * 32 + col] = a1;
    }
}

// ---------- pass 2: deg/rp/rpe/dinv + ceil16-PADDED slotted CSR + H1 scale ----------
__global__ __launch_bounds__(512) void k_csr(const unsigned* __restrict__ packed,
                                             const int* __restrict__ gcnt,
                                             int* __restrict__ rp, int* __restrict__ rpe,
                                             float* __restrict__ dinv,
                                             int* __restrict__ csr,
                                             const float* __restrict__ H1u,
                                             __hip_bfloat16* __restrict__ H1s) {
    __shared__ int deg[128];
    __shared__ int nb0[128];
    __shared__ float dsh[128];
    __shared__ int wsum0;
    __shared__ int ntot;
    __shared__ int lcsr[CCAP] __attribute__((aligned(16)));
    int t = threadIdx.x;
    int b = blockIdx.x;
    if (t < 128) deg[t] = 0;
    __syncthreads();
    int n = gcnt[b];
    const unsigned* pb = packed + (size_t)b * CAP;
    unsigned pv[3][4];
    int rk[3][4];
#pragma unroll
    for (int g = 0; g < 3; g++) {
        int i0 = 4 * (t + g * 512);
        if (i0 < n) {
            if (i0 + 3 < n) {
                uint4 p = *(const uint4*)(pb + i0);
                pv[g][0] = p.x; pv[g][1] = p.y; pv[g][2] = p.z; pv[g][3] = p.w;
            } else {
#pragma unroll
                for (int k = 0; k < 4; k++) pv[g][k] = (i0 + k < n) ? pb[i0 + k] : 0u;
            }
#pragma unroll
            for (int k = 0; k < 4; k++)
                if (i0 + k < n) rk[g][k] = atomicAdd(&deg[pv[g][k] >> 17], 1);
        }
    }
    __syncthreads();
    // wave-level scan over padded degrees (threads 0..127 = waves 0,1)
    int lane = t & 63;
    int d = (t < 128) ? deg[t] : 0;
    int p16 = (d + 15) & ~15;
    int v = (t < 128) ? p16 : 0;
#pragma unroll
    for (int d2 = 1; d2 < 64; d2 <<= 1) {
        int o = __shfl_up(v, d2);
        if (lane >= d2) v += o;
    }
    if (t == 63) wsum0 = v;
    __syncthreads();
    if (t < 128) {
        int inc = v + ((t >= 64) ? wsum0 : 0);
        int l0 = inc - p16;
        nb0[t] = l0;
        float di = rsqrtf((float)d + 1.0f);
        dsh[t] = di;
        int node = b * 128 + t;
        if (node < N_NODES) {
            rp[node] = b * CCAP + l0;
            rpe[node] = b * CCAP + l0 + p16;
            dinv[node] = di;
        }
        for (int j = d; j < p16; j++) lcsr[l0 + j] = N_NODES;   // dummy pads
        if (t == 127) ntot = l0 + p16;
    }
    __syncthreads();
#pragma unroll
    for (int g = 0; g < 3; g++) {
        int i0 = 4 * (t + g * 512);
        if (i0 < n) {
#pragma unroll
            for (int k = 0; k < 4; k++) {
                if (i0 + k < n) {
                    unsigned p = pv[g][k];
                    lcsr[nb0[p >> 17] + rk[g][k]] = (int)(p & 0x1FFFFu);
                }
            }
        }
    }
    __syncthreads();
    int nq = (ntot + 3) >> 2;
    int4* dst4 = (int4*)(csr + (size_t)b * CCAP);
    const int4* sl4 = (const int4*)lcsr;
    for (int i = t; i < nq; i += 512) dst4[i] = sl4[i];
    // ---- H1 scale epilogue: 128 rows x 32 f32 -> bf16, x dinv ----
    for (int i = t; i < 1024; i += 512) {
        int row = i >> 3, q = i & 7;
        int node = b * 128 + row;
        if (node < N_NODES) {
            float4 fv = ((const float4*)H1u)[(size_t)node * 8 + q];
            float di = dsh[row];
            __hip_bfloat16 tmp[4];
            tmp[0] = __float2bfloat16(fv.x * di);
            tmp[1] = __float2bfloat16(fv.y * di);
            tmp[2] = __float2bfloat16(fv.z * di);
            tmp[3] = __float2bfloat16(fv.w * di);
            *(uint2*)(H1s + (size_t)node * 32 + q * 4) = *(uint2*)tmp;
        }
    }
    // dummy H1s row (read by gather pads) = zeros
    if (b == 0 && t < 16) ((unsigned*)(H1s + (size_t)N_NODES * 32))[t] = 0u;
}

// ---------- aggregation: 4 NODES PER WAVE (16 lanes/node: 4 edge-slots x 4 f-quads) ----
// Amortizes per-node overhead (prologue, butterfly, epilogue) 4x. ceil16-padded
// CSR + dummy zero row -> no inner guards at all; only the per-quarter outer
// loop bound diverges (exec-masked).
__global__ void k_gather(const __hip_bfloat16* __restrict__ Hs, const float* __restrict__ dinv,
                         const int* __restrict__ rp, const int* __restrict__ rpe,
                         const int* __restrict__ csr,
                         const float* __restrict__ bias, float* __restrict__ hout) {
    int lane = threadIdx.x & 63;
    int fb = lane & 3;                           // feature quad (uint4) within row
    int qn = lane >> 4;                          // node slot within wave (0..3)
    int wave = (blockIdx.x * 256 + threadIdx.x) >> 6;
    int wid = wave * 4 + qn;                     // grid exact: 6250 blocks * 16 nodes
    const uint4* H4 = (const uint4*)Hs;          // row = 4 x uint4 (64B)
    int beg = rp[wid];
    int pdeg = rpe[wid] - beg;                   // ceil16(deg)
    int sidx = (lane & 48) | ((lane >> 2) & 3);  // shfl base: quarter | edge-slot
    float a0=0.f,a1=0.f,a2=0.f,a3=0.f,a4=0.f,a5=0.f,a6=0.f,a7=0.f;
    for (int eb = 0; eb < pdeg; eb += 16) {      // per-quarter bound (divergent, masked)
        int cv = csr[beg + eb + (lane & 15)];    // 16 edges per node per load
#pragma unroll
        for (int k = 0; k < 4; k++) {
            int src = __shfl(cv, sidx + 4 * k);  // stays within own 16-lane group
            uint4 v = H4[(unsigned)src * 4u + fb];
            a0 += blo(v.x); a1 += bhi(v.x);
            a2 += blo(v.y); a3 += bhi(v.y);
            a4 += blo(v.z); a5 += bhi(v.z);
            a6 += blo(v.w); a7 += bhi(v.w);
        }
    }
    // reduce over the 4 edge-slots (lane bits 2-3)
#pragma unroll
    for (int m = 4; m <= 8; m <<= 1) {
        a0 += __shfl_xor(a0, m); a1 += __shfl_xor(a1, m);
        a2 += __shfl_xor(a2, m); a3 += __shfl_xor(a3, m);
        a4 += __shfl_xor(a4, m); a5 += __shfl_xor(a5, m);
        a6 += __shfl_xor(a6, m); a7 += __shfl_xor(a7, m);
    }
    if (((lane >> 2) & 3) == 0) {                // 4 lanes per node (fb 0..3)
        float di = dinv[wid];
        uint4 vw = H4[(unsigned)wid * 4u + fb];
        float4 bA = *(const float4*)(bias + fb * 8);
        float4 bB = *(const float4*)(bias + fb * 8 + 4);
        float4 oA, oB;
        oA.x = fmaxf((a0 + blo(vw.x)) * di + bA.x, 0.f);
        oA.y = fmaxf((a1 + bhi(vw.x)) * di + bA.y, 0.f);
        oA.z = fmaxf((a2 + blo(vw.y)) * di + bA.z, 0.f);
        oA.w = fmaxf((a3 + bhi(vw.y)) * di + bA.w, 0.f);
        oB.x = fmaxf((a4 + blo(vw.z)) * di + bB.x, 0.f);
        oB.y = fmaxf((a5 + bhi(vw.z)) * di + bB.y, 0.f);
        oB.z = fmaxf((a6 + blo(vw.w)) * di + bB.z, 0.f);
        oB.w = fmaxf((a7 + bhi(vw.w)) * di + bB.w, 0.f);
        float* o = hout + (size_t)wid * 32 + fb * 8;
        *(float4*)o = oA;
        *(float4*)(o + 4) = oB;
    }
}

// ---------- H2s = bf16( (h1 @ W2) * dinv[row] ) ----------
__global__ void k_gemm2(const float* __restrict__ h1, const float* __restrict__ W2,
                        const float* __restrict__ dinv, __hip_bfloat16* __restrict__ H2s) {
    __shared__ float Ws[32 * 32];
    __shared__ float xs[32 * 32];
    int t = threadIdx.x;
    ((float4*)Ws)[t] = ((const float4*)W2)[t];
    int row0 = blockIdx.x * 32;
    ((float4*)xs)[t] = ((const float4*)(h1 + (size_t)row0 * 32))[t];
    __syncthreads();
    int col = t & 31;
    int rb = (t >> 5) * 4;
    float a0 = 0.f, a1 = 0.f, a2 = 0.f, a3 = 0.f;
#pragma unroll
    for (int k = 0; k < 32; k++) {
        float w = Ws[k * 32 + col];
        a0 += xs[(rb + 0) * 32 + k] * w;
        a1 += xs[(rb + 1) * 32 + k] * w;
        a2 += xs[(rb + 2) * 32 + k] * w;
        a3 += xs[(rb + 3) * 32 + k] * w;
    }
    int r = row0 + rb;
    __hip_bfloat16* o = H2s + (size_t)r * 32 + col;
    o[0]  = __float2bfloat16(a0 * dinv[r + 0]);
    o[32] = __float2bfloat16(a1 * dinv[r + 1]);
    o[64] = __float2bfloat16(a2 * dinv[r + 2]);
    o[96] = __float2bfloat16(a3 * dinv[r + 3]);
    // dummy H2s row (read by gather2 pads) = zeros
    if (blockIdx.x == 0 && t < 16) ((unsigned*)(H2s + (size_t)N_NODES * 32))[t] = 0u;
}

// ---------- per-graph mean pool + head (no atomics; batch is sorted) ----------
__global__ __launch_bounds__(256) void k_pool(const float* __restrict__ h2,
                                              const int* __restrict__ batch,
                                              const float* __restrict__ Wl,
                                              const float* __restrict__ bl,
                                              float* __restrict__ out) {
    __shared__ float red[256];
    __shared__ float pooled[32];
    int g = blockIdx.x;
    int t = threadIdx.x;
    int lo = 0, hi = N_NODES;
    while (lo < hi) { int m = (lo + hi) >> 1; if (batch[m] < g) lo = m + 1; else hi = m; }
    int s = lo;
    hi = N_NODES;
    while (lo < hi) { int m = (lo + hi) >> 1; if (batch[m] < g + 1) lo = m + 1; else hi = m; }
    int e = lo;
    int f = t & 31, r0 = t >> 5;
    float acc = 0.f;
    for (int r = s + r0; r < e; r += 8) acc += h2[(size_t)r * 32 + f];
    red[t] = acc;
    __syncthreads();
    for (int off = 128; off >= 32; off >>= 1) {
        if (t < off) red[t] += red[t + off];
        __syncthreads();
    }
    if (t < 32) pooled[t] = red[t] / fmaxf((float)(e - s), 1.0f);
    __syncthreads();
    if (t < 2) {
        float a = bl[t];
#pragma unroll
        for (int k = 0; k < 32; k++) a += pooled[k] * Wl[k * 2 + t];
        out[g * 2 + t] = a;
    }
}

extern "C" void kernel_launch(void* const* d_in, const int* in_sizes, int n_in,
                              void* d_out, int out_size, void* d_ws, size_t ws_size,
                              hipStream_t stream) {
    const float* x    = (const float*)d_in[0];
    const int*   ei   = (const int*)d_in[1];
    const int*   batch= (const int*)d_in[2];
    const float* W1   = (const float*)d_in[3];
    const float* b1   = (const float*)d_in[4];
    const float* W2   = (const float*)d_in[5];
    const float* b2   = (const float*)d_in[6];
    const float* Wl   = (const float*)d_in[7];
    const float* bl   = (const float*)d_in[8];
    float* out = (float*)d_out;

    char* w = (char*)d_ws;
    size_t off = 0;
    auto take = [&](size_t bytes) -> char* {
        char* p = w + off;
        off = (off + bytes + 255) & ~(size_t)255;
        return p;
    };
    // +1 dummy row on H1s/H2s for gather pads
    __hip_bfloat16* H1s = (__hip_bfloat16*)take((size_t)(N_NODES + 1) * 32 * 2);
    // h1: H1u (f32, fatA->csr), then relu'd h1 (gather1->gemm2), then h2 (gather2->pool)
    float*          h1  = (float*)take((size_t)N_NODES * 32 * 4);
    // packed (14.4 MB) and H2s (6.4 MB) alias: packed dies at k_csr; H2s born at k_gemm2.
    char*           shared = take((size_t)NBUK * CAP * 4);
    unsigned*       packed = (unsigned*)shared;
    __hip_bfloat16* H2s    = (__hip_bfloat16*)shared;
    int*      csr    = (int*)  take((size_t)NBUK * CCAP * 4 + 1024);   // +pad
    float*    dinv   = (float*)take((size_t)N_NODES * 4);
    int*      rp     = (int*)  take((size_t)N_NODES * 4);
    int*      rpe    = (int*)  take((size_t)N_NODES * 4);
    int*      gcnt   = (int*)  take((size_t)NBUK * 4);

    hipMemsetAsync(gcnt, 0, (size_t)NBUK * 4, stream);

    k_fatA  <<<FILL_BLOCKS + GEMM1_BLOCKS, 1024, 0, stream>>>(ei, gcnt, packed, x, W1, h1);
    k_csr   <<<NBUK, 512, 0, stream>>>(packed, gcnt, rp, rpe, dinv, csr, h1, H1s);
    k_gather<<<N_NODES / 16, 256, 0, stream>>>(H1s, dinv, rp, rpe, csr, b1, h1);
    k_gemm2 <<<N_NODES / 32, 256, 0, stream>>>(h1, W2, dinv, H2s);
    k_gather<<<N_NODES / 16, 256, 0, stream>>>(H2s, dinv, rp, rpe, csr, b2, h1);
    k_pool  <<<N_GRAPHS, 256, 0, stream>>>(h1, batch, Wl, bl, out);
}

// Round 13
// 248.341 us; speedup vs baseline: 1.1382x; 1.0267x over previous
//
#include <hip/hip_runtime.h>
#include <hip/hip_bf16.h>

#define N_NODES 100000
#define N_EDGES 3200000
#define N_GRAPHS 512
#define NBUK 782               // dst buckets of 128 nodes
#define CAP 4608               // packed slots per bucket (mean 4096, sigma~64)
#define CCAP 5632              // csr slots per bucket (ceil16-padded degs, mean ~5120)
#define FILL_CHUNK 8192
#define FILL_BLOCKS ((N_EDGES + FILL_CHUNK - 1) / FILL_CHUNK)   // 391
#define GEMM1_BLOCKS ((N_NODES + 63) / 64)                      // 1563

__device__ __forceinline__ float blo(unsigned v) { return __uint_as_float(v << 16); }
__device__ __forceinline__ float bhi(unsigned v) { return __uint_as_float(v & 0xffff0000u); }

// ---------- fat pass 1: binfill (blocks 0..390)  ||  gemm1 unscaled (rest) ----------
// Writeout now uses 16-lane groups (one bucket run each): 64 concurrent runs,
// ~12 outer iterations at 66% lane utilization (was 49 iterations at 16%).
__global__ __launch_bounds__(1024) void k_fatA(const int* __restrict__ ei,
                                               int* __restrict__ gcnt,
                                               unsigned* __restrict__ packed,
                                               const float* __restrict__ x,
                                               const float* __restrict__ W1,
                                               float* __restrict__ H1u) {
    __shared__ __align__(16) char smem[49152];
    int t = threadIdx.x;
    if (blockIdx.x < FILL_BLOCKS) {
        unsigned* buf = (unsigned*)smem;                       // 32768 B
        int* h    = (int*)(smem + 32768);
        int* base = (int*)(smem + 35896);
        int* sb   = (int*)(smem + 39024);
        int* ws   = (int*)(smem + 42152);                      // 16 wave sums
        for (int i = t; i < NBUK; i += 1024) h[i] = 0;
        __syncthreads();
        int s0 = blockIdx.x * FILL_CHUNK;
        int ng = min(FILL_CHUNK, N_EDGES - s0) >> 2;
        const int4* src4 = (const int4*)(ei + s0);
        const int4* dst4 = (const int4*)(ei + N_EDGES + s0);
        int4 sv[2], dv[2];
        int  rk[2][4];
#pragma unroll
        for (int g = 0; g < 2; g++) {
            int gi = t + g * 1024;
            if (gi < ng) {
                sv[g] = src4[gi];
                dv[g] = dst4[gi];
                rk[g][0] = atomicAdd(&h[dv[g].x >> 7], 1);
                rk[g][1] = atomicAdd(&h[dv[g].y >> 7], 1);
                rk[g][2] = atomicAdd(&h[dv[g].z >> 7], 1);
                rk[g][3] = atomicAdd(&h[dv[g].w >> 7], 1);
            }
        }
        __syncthreads();
        for (int i = t; i < NBUK; i += 1024) {
            int c = h[i];
            base[i] = c ? atomicAdd(&gcnt[i], c) : 0;
        }
        // wave-level exclusive scan of h[0..NBUK)
        int lane = t & 63, wv = t >> 6;
        int hval = (t < NBUK) ? h[t] : 0;
        int v = hval;
#pragma unroll
        for (int d2 = 1; d2 < 64; d2 <<= 1) {
            int o = __shfl_up(v, d2);
            if (lane >= d2) v += o;
        }
        if (lane == 63) ws[wv] = v;
        __syncthreads();
        if (wv == 0) {
            int s = (lane < 16) ? ws[lane] : 0;
            int sv2 = s;
#pragma unroll
            for (int d2 = 1; d2 < 16; d2 <<= 1) {
                int o = __shfl_up(sv2, d2);
                if (lane >= d2) sv2 += o;
            }
            if (lane < 16) ws[lane] = sv2 - s;   // exclusive wave offsets
        }
        __syncthreads();
        if (t < NBUK) sb[t] = v + ws[wv] - hval;
        __syncthreads();
#pragma unroll
        for (int g = 0; g < 2; g++) {
            int gi = t + g * 1024;
            if (gi < ng) {
                int s[4] = {sv[g].x, sv[g].y, sv[g].z, sv[g].w};
                int d[4] = {dv[g].x, dv[g].y, dv[g].z, dv[g].w};
#pragma unroll
                for (int k = 0; k < 4; k++) {
                    int bk = d[k] >> 7;
                    buf[sb[bk] + rk[g][k]] = (unsigned)s[k] | (((unsigned)d[k] & 127u) << 17);
                }
            }
        }
        __syncthreads();
        int g16 = t >> 4;                        // 64 16-lane groups
        int l16 = t & 15;
        for (int bk = g16; bk < NBUK; bk += 64) {
            int c = h[bk];
            if (!c) continue;
            unsigned* gp = packed + (size_t)bk * CAP + base[bk];
            int lb = sb[bk];
            for (int j = l16; j < c; j += 16) gp[j] = buf[lb + j];
        }
    } else {
        // ---- gemm1u branch: H1u = x @ W1 (f32, unscaled), 64 rows/block, 2 rows/thread ----
        float* Ws = (float*)smem;              // 16384 B
        float* xs = (float*)(smem + 16384);    // 32768 B
        int b = blockIdx.x - FILL_BLOCKS;
        ((float4*)Ws)[t] = ((const float4*)W1)[t];
        int row0 = b * 64;
        const float4* x4 = (const float4*)(x + (size_t)row0 * 128);
        float4* xs4 = (float4*)xs;
        int maxr = min(64, N_NODES - row0);
        int nf4 = maxr * 32;
#pragma unroll
        for (int i = 0; i < 8; i++) {
            int idx = t + i * 1024;
            if (idx < nf4) xs4[idx] = x4[idx];
        }
        __syncthreads();
        int col = t & 31;
        int g = t >> 5;
        int r0 = 2 * g, r1 = 2 * g + 1;
        const float4* xa4 = xs4 + r0 * 32;
        const float4* xb4 = xs4 + r1 * 32;
        float a0 = 0.f, a1 = 0.f;
#pragma unroll 8
        for (int k4 = 0; k4 < 32; k4++) {
            float4 xa = xa4[k4];
            float4 xb = xb4[k4];
            float w0 = Ws[(k4 * 4 + 0) * 32 + col];
            float w1 = Ws[(k4 * 4 + 1) * 32 + col];
            float w2 = Ws[(k4 * 4 + 2) * 32 + col];
            float w3 = Ws[(k4 * 4 + 3) * 32 + col];
            a0 += xa.x * w0 + xa.y * w1 + xa.z * w2 + xa.w * w3;
            a1 += xb.x * w0 + xb.y * w1 + xb.z * w2 + xb.w * w3;
        }
        if (row0 + r0 < N_NODES) H1u[(size_t)(row0 + r0) * 32 + col] = a0;
        if (row0 + r1 < N_NODES) H1u[(size_t)(row0 + r1) * 32 + col] = a1;
    }
}

// ---------- pass 2: deg/rp/rpe/dinv + ceil16-PADDED slotted CSR + H1 scale ----------
// Rank atomics split across 4 LDS histogram copies (one per 128-thread quarter):
// per-address contention 32 -> 8. Copies merged via 4-term exclusive prefix.
__global__ __launch_bounds__(512) void k_csr(const unsigned* __restrict__ packed,
                                             const int* __restrict__ gcnt,
                                             int* __restrict__ rp, int* __restrict__ rpe,
                                             float* __restrict__ dinv,
                                             int* __restrict__ csr,
                                             const float* __restrict__ H1u,
                                             __hip_bfloat16* __restrict__ H1s) {
    __shared__ int deg4[4][128];
    __shared__ int nb0[128];
    __shared__ float dsh[128];
    __shared__ int wsum0;
    __shared__ int ntot;
    __shared__ int lcsr[CCAP] __attribute__((aligned(16)));
    int t = threadIdx.x;
    int b = blockIdx.x;
    deg4[t >> 7][t & 127] = 0;
    __syncthreads();
    int n = gcnt[b];
    const unsigned* pb = packed + (size_t)b * CAP;
    int cp = t >> 7;                             // this thread's histogram copy
    unsigned pv[3][4];
    int rk[3][4];
#pragma unroll
    for (int g = 0; g < 3; g++) {
        int i0 = 4 * (t + g * 512);
        if (i0 < n) {
            if (i0 + 3 < n) {
                uint4 p = *(const uint4*)(pb + i0);
                pv[g][0] = p.x; pv[g][1] = p.y; pv[g][2] = p.z; pv[g][3] = p.w;
            } else {
#pragma unroll
                for (int k = 0; k < 4; k++) pv[g][k] = (i0 + k < n) ? pb[i0 + k] : 0u;
            }
#pragma unroll
            for (int k = 0; k < 4; k++)
                if (i0 + k < n) rk[g][k] = atomicAdd(&deg4[cp][pv[g][k] >> 17], 1);
        }
    }
    __syncthreads();
    // merge copies + wave-level scan over padded degrees
    int lane = t & 63;
    int d = 0, e1 = 0, e2 = 0, e3 = 0;
    if (t < 128) {
        int c0 = deg4[0][t], c1 = deg4[1][t], c2 = deg4[2][t], c3 = deg4[3][t];
        e1 = c0; e2 = c0 + c1; e3 = e2 + c2; d = e3 + c3;
    }
    int p16 = (d + 15) & ~15;
    int v = (t < 128) ? p16 : 0;
#pragma unroll
    for (int d2 = 1; d2 < 64; d2 <<= 1) {
        int o = __shfl_up(v, d2);
        if (lane >= d2) v += o;
    }
    if (t == 63) wsum0 = v;
    __syncthreads();
    if (t < 128) {
        deg4[0][t] = 0; deg4[1][t] = e1; deg4[2][t] = e2; deg4[3][t] = e3;  // exclusive copy bases
        int inc = v + ((t >= 64) ? wsum0 : 0);
        int l0 = inc - p16;
        nb0[t] = l0;
        float di = rsqrtf((float)d + 1.0f);
        dsh[t] = di;
        int node = b * 128 + t;
        if (node < N_NODES) {
            rp[node] = b * CCAP + l0;
            rpe[node] = b * CCAP + l0 + p16;
            dinv[node] = di;
        }
        for (int j = d; j < p16; j++) lcsr[l0 + j] = N_NODES;   // dummy pads
        if (t == 127) ntot = l0 + p16;
    }
    __syncthreads();
#pragma unroll
    for (int g = 0; g < 3; g++) {
        int i0 = 4 * (t + g * 512);
        if (i0 < n) {
#pragma unroll
            for (int k = 0; k < 4; k++) {
                if (i0 + k < n) {
                    unsigned p = pv[g][k];
                    int dst = p >> 17;
                    lcsr[nb0[dst] + deg4[cp][dst] + rk[g][k]] = (int)(p & 0x1FFFFu);
                }
            }
        }
    }
    __syncthreads();
    int nq = (ntot + 3) >> 2;
    int4* dst4 = (int4*)(csr + (size_t)b * CCAP);
    const int4* sl4 = (const int4*)lcsr;
    for (int i = t; i < nq; i += 512) dst4[i] = sl4[i];
    // ---- H1 scale epilogue: 128 rows x 32 f32 -> bf16, x dinv ----
    for (int i = t; i < 1024; i += 512) {
        int row = i >> 3, q = i & 7;
        int node = b * 128 + row;
        if (node < N_NODES) {
            float4 fv = ((const float4*)H1u)[(size_t)node * 8 + q];
            float di = dsh[row];
            __hip_bfloat16 tmp[4];
            tmp[0] = __float2bfloat16(fv.x * di);
            tmp[1] = __float2bfloat16(fv.y * di);
            tmp[2] = __float2bfloat16(fv.z * di);
            tmp[3] = __float2bfloat16(fv.w * di);
            *(uint2*)(H1s + (size_t)node * 32 + q * 4) = *(uint2*)tmp;
        }
    }
    // dummy H1s row (read by gather pads) = zeros
    if (b == 0 && t < 16) ((unsigned*)(H1s + (size_t)N_NODES * 32))[t] = 0u;
}

// ---------- aggregation: 4 nodes/wave + 32-edge unrolled main loop (int2 csr) ----------
// Per outer iter: 1 int2 csr load + 8 shfl + 8 independent uint4 row loads
// (double the MLP window, half the loop overhead of the 16-edge version).
__global__ void k_gather(const __hip_bfloat16* __restrict__ Hs, const float* __restrict__ dinv,
                         const int* __restrict__ rp, const int* __restrict__ rpe,
                         const int* __restrict__ csr,
                         const float* __restrict__ bias, float* __restrict__ hout) {
    int lane = threadIdx.x & 63;
    int fb = lane & 3;                           // feature quad (uint4) within row
    int qn = lane >> 4;                          // node slot within wave (0..3)
    int wave = (blockIdx.x * 256 + threadIdx.x) >> 6;
    int wid = wave * 4 + qn;                     // grid exact: 6250 blocks * 16 nodes
    const uint4* H4 = (const uint4*)Hs;          // row = 4 x uint4 (64B)
    int beg = rp[wid];
    int pdeg = rpe[wid] - beg;                   // ceil16(deg)
    int grp = lane & 48;
    int es = (lane >> 2) & 3;
    int es4 = es * 4;
    float a0=0.f,a1=0.f,a2=0.f,a3=0.f,a4=0.f,a5=0.f,a6=0.f,a7=0.f;
    int e = 0;
    for (; e + 32 <= pdeg; e += 32) {            // group-uniform bound (masked)
        int2 cv2 = *(const int2*)(csr + beg + e + 2 * (lane & 15));
#pragma unroll
        for (int k = 0; k < 8; k++) {
            int src = __shfl((k & 1) ? cv2.y : cv2.x, grp | (es4 + (k >> 1)));
            uint4 v = H4[(unsigned)src * 4u + fb];
            a0 += blo(v.x); a1 += bhi(v.x);
            a2 += blo(v.y); a3 += bhi(v.y);
            a4 += blo(v.z); a5 += bhi(v.z);
            a6 += blo(v.w); a7 += bhi(v.w);
        }
    }
    if (e < pdeg) {                              // at most one 16-edge tail
        int cv = csr[beg + e + (lane & 15)];
#pragma unroll
        for (int k = 0; k < 4; k++) {
            int src = __shfl(cv, grp | (es + 4 * k));
            uint4 v = H4[(unsigned)src * 4u + fb];
            a0 += blo(v.x); a1 += bhi(v.x);
            a2 += blo(v.y); a3 += bhi(v.y);
            a4 += blo(v.z); a5 += bhi(v.z);
            a6 += blo(v.w); a7 += bhi(v.w);
        }
    }
    // reduce over the 4 edge-slots (lane bits 2-3)
#pragma unroll
    for (int m = 4; m <= 8; m <<= 1) {
        a0 += __shfl_xor(a0, m); a1 += __shfl_xor(a1, m);
        a2 += __shfl_xor(a2, m); a3 += __shfl_xor(a3, m);
        a4 += __shfl_xor(a4, m); a5 += __shfl_xor(a5, m);
        a6 += __shfl_xor(a6, m); a7 += __shfl_xor(a7, m);
    }
    if (es == 0) {                               // 4 lanes per node (fb 0..3)
        float di = dinv[wid];
        uint4 vw = H4[(unsigned)wid * 4u + fb];
        float4 bA = *(const float4*)(bias + fb * 8);
        float4 bB = *(const float4*)(bias + fb * 8 + 4);
        float4 oA, oB;
        oA.x = fmaxf((a0 + blo(vw.x)) * di + bA.x, 0.f);
        oA.y = fmaxf((a1 + bhi(vw.x)) * di + bA.y, 0.f);
        oA.z = fmaxf((a2 + blo(vw.y)) * di + bA.z, 0.f);
        oA.w = fmaxf((a3 + bhi(vw.y)) * di + bA.w, 0.f);
        oB.x = fmaxf((a4 + blo(vw.z)) * di + bB.x, 0.f);
        oB.y = fmaxf((a5 + bhi(vw.z)) * di + bB.y, 0.f);
        oB.z = fmaxf((a6 + blo(vw.w)) * di + bB.z, 0.f);
        oB.w = fmaxf((a7 + bhi(vw.w)) * di + bB.w, 0.f);
        float* o = hout + (size_t)wid * 32 + fb * 8;
        *(float4*)o = oA;
        *(float4*)(o + 4) = oB;
    }
}

// ---------- H2s = bf16( (h1 @ W2) * dinv[row] ) ----------
__global__ void k_gemm2(const float* __restrict__ h1, const float* __restrict__ W2,
                        const float* __restrict__ dinv, __hip_bfloat16* __restrict__ H2s) {
    __shared__ float Ws[32 * 32];
    __shared__ float xs[32 * 32];
    int t = threadIdx.x;
    ((float4*)Ws)[t] = ((const float4*)W2)[t];
    int row0 = blockIdx.x * 32;
    ((float4*)xs)[t] = ((const float4*)(h1 + (size_t)row0 * 32))[t];
    __syncthreads();
    int col = t & 31;
    int rb = (t >> 5) * 4;
    float a0 = 0.f, a1 = 0.f, a2 = 0.f, a3 = 0.f;
#pragma unroll
    for (int k = 0; k < 32; k++) {
        float w = Ws[k * 32 + col];
        a0 += xs[(rb + 0) * 32 + k] * w;
        a1 += xs[(rb + 1) * 32 + k] * w;
        a2 += xs[(rb + 2) * 32 + k] * w;
        a3 += xs[(rb + 3) * 32 + k] * w;
    }
    int r = row0 + rb;
    __hip_bfloat16* o = H2s + (size_t)r * 32 + col;
    o[0]  = __float2bfloat16(a0 * dinv[r + 0]);
    o[32] = __float2bfloat16(a1 * dinv[r + 1]);
    o[64] = __float2bfloat16(a2 * dinv[r + 2]);
    o[96] = __float2bfloat16(a3 * dinv[r + 3]);
    // dummy H2s row (read by gather2 pads) = zeros
    if (blockIdx.x == 0 && t < 16) ((unsigned*)(H2s + (size_t)N_NODES * 32))[t] = 0u;
}

// ---------- per-graph mean pool + head (no atomics; batch is sorted) ----------
__global__ __launch_bounds__(256) void k_pool(const float* __restrict__ h2,
                                              const int* __restrict__ batch,
                                              const float* __restrict__ Wl,
                                              const float* __restrict__ bl,
                                              float* __restrict__ out) {
    __shared__ float red[256];
    __shared__ float pooled[32];
    int g = blockIdx.x;
    int t = threadIdx.x;
    int lo = 0, hi = N_NODES;
    while (lo < hi) { int m = (lo + hi) >> 1; if (batch[m] < g) lo = m + 1; else hi = m; }
    int s = lo;
    hi = N_NODES;
    while (lo < hi) { int m = (lo + hi) >> 1; if (batch[m] < g + 1) lo = m + 1; else hi = m; }
    int e = lo;
    int f = t & 31, r0 = t >> 5;
    float acc = 0.f;
    for (int r = s + r0; r < e; r += 8) acc += h2[(size_t)r * 32 + f];
    red[t] = acc;
    __syncthreads();
    for (int off = 128; off >= 32; off >>= 1) {
        if (t < off) red[t] += red[t + off];
        __syncthreads();
    }
    if (t < 32) pooled[t] = red[t] / fmaxf((float)(e - s), 1.0f);
    __syncthreads();
    if (t < 2) {
        float a = bl[t];
#pragma unroll
        for (int k = 0; k < 32; k++) a += pooled[k] * Wl[k * 2 + t];
        out[g * 2 + t] = a;
    }
}

extern "C" void kernel_launch(void* const* d_in, const int* in_sizes, int n_in,
                              void* d_out, int out_size, void* d_ws, size_t ws_size,
                              hipStream_t stream) {
    const float* x    = (const float*)d_in[0];
    const int*   ei   = (const int*)d_in[1];
    const int*   batch= (const int*)d_in[2];
    const float* W1   = (const float*)d_in[3];
    const float* b1   = (const float*)d_in[4];
    const float* W2   = (const float*)d_in[5];
    const float* b2   = (const float*)d_in[6];
    const float* Wl   = (const float*)d_in[7];
    const float* bl   = (const float*)d_in[8];
    float* out = (float*)d_out;

    char* w = (char*)d_ws;
    size_t off = 0;
    auto take = [&](size_t bytes) -> char* {
        char* p = w + off;
        off = (off + bytes + 255) & ~(size_t)255;
        return p;
    };
    // +1 dummy row on H1s/H2s for gather pads
    __hip_bfloat16* H1s = (__hip_bfloat16*)take((size_t)(N_NODES + 1) * 32 * 2);
    // h1: H1u (f32, fatA->csr), then relu'd h1 (gather1->gemm2), then h2 (gather2->pool)
    float*          h1  = (float*)take((size_t)N_NODES * 32 * 4);
    // packed (14.4 MB) and H2s (6.4 MB) alias: packed dies at k_csr; H2s born at k_gemm2.
    char*           shared = take((size_t)NBUK * CAP * 4);
    unsigned*       packed = (unsigned*)shared;
    __hip_bfloat16* H2s    = (__hip_bfloat16*)shared;
    int*      csr    = (int*)  take((size_t)NBUK * CCAP * 4 + 1024);   // +pad
    float*    dinv   = (float*)take((size_t)N_NODES * 4);
    int*      rp     = (int*)  take((size_t)N_NODES * 4);
    int*      rpe    = (int*)  take((size_t)N_NODES * 4);
    int*      gcnt   = (int*)  take((size_t)NBUK * 4);

    hipMemsetAsync(gcnt, 0, (size_t)NBUK * 4, stream);

    k_fatA  <<<FILL_BLOCKS + GEMM1_BLOCKS, 1024, 0, stream>>>(ei, gcnt, packed, x, W1, h1);
    k_csr   <<<NBUK, 512, 0, stream>>>(packed, gcnt, rp, rpe, dinv, csr, h1, H1s);
    k_gather<<<N_NODES / 16, 256, 0, stream>>>(H1s, dinv, rp, rpe, csr, b1, h1);
    k_gemm2 <<<N_NODES / 32, 256, 0, stream>>>(h1, W2, dinv, H2s);
    k_gather<<<N_NODES / 16, 256, 0, stream>>>(H2s, dinv, rp, rpe, csr, b2, h1);
    k_pool  <<<N_GRAPHS, 256, 0, stream>>>(h1, batch, Wl, bl, out);
}